// Round 5
// baseline (372.595 us; speedup 1.0000x reference)
//
#include <hip/hip_runtime.h>
#include <hip/hip_bf16.h>
#include <hip/hip_cooperative_groups.h>
#include <cstdint>

namespace cg = cooperative_groups;

typedef unsigned short ushort_t;
typedef __bf16 bf16x8 __attribute__((ext_vector_type(8)));
typedef float f32x4 __attribute__((ext_vector_type(4)));

#define B_   16
#define S_   512
#define D_   768
#define E_   128

__device__ inline ushort_t f2b(float f) {
    uint32_t u = __builtin_bit_cast(uint32_t, f);
    uint32_t r = (u + 0x7fffu + ((u >> 16) & 1u)) >> 16;   // RNE
    return (ushort_t)r;
}
__device__ inline float b2f(ushort_t u) {
    uint32_t v = ((uint32_t)u) << 16;
    return __builtin_bit_cast(float, v);
}
__device__ inline float bl(uint32_t u) {
    uint32_t v = u << 16;
    return __builtin_bit_cast(float, v);
}
__device__ inline float bh(uint32_t u) {
    uint32_t v = u & 0xffff0000u;
    return __builtin_bit_cast(float, v);
}

union SMem {
    float tp[32][33];                                  // transpose tile (4224 B)
    struct { ushort_t As[64 * 32]; ushort_t Bs[64 * 32]; } g;  // gemm staging (8192 B)
};

// 64x64 block-tile bf16 MFMA gemm unit (wave tile 32x32, BK=32), m97-style
// LDS staging via global_load_lds width 16. Block-uniform call.
__device__ __forceinline__ void gemm_unit(
    const ushort_t* __restrict__ A, const ushort_t* __restrict__ Bt,
    const float* __restrict__ bias, ushort_t* __restrict__ outp,
    int tileM, int tileN, int N, int K, int doRelu,
    ushort_t* As, ushort_t* Bs, int t)
{
    int lane = t & 63, wave = t >> 6;
    int wm = (wave >> 1) * 32, wn = (wave & 1) * 32;
    int l15 = lane & 15, quad = lane >> 4;
    int srow = t >> 2, sc8 = (t & 3) << 3;

    const ushort_t* gA = A + (size_t)tileM * K;
    const ushort_t* gB = Bt + (size_t)tileN * K;

    f32x4 acc[2][2];
#pragma unroll
    for (int a = 0; a < 2; ++a)
#pragma unroll
        for (int b = 0; b < 2; ++b) {
            acc[a][b][0] = 0.f; acc[a][b][1] = 0.f;
            acc[a][b][2] = 0.f; acc[a][b][3] = 0.f;
        }

    for (int k0 = 0; k0 < K; k0 += 32) {
        __builtin_amdgcn_global_load_lds(
            (const __attribute__((address_space(1))) void*)(gA + (size_t)srow * K + k0 + sc8),
            (__attribute__((address_space(3))) void*)(As + t * 8), 16, 0, 0);
        __builtin_amdgcn_global_load_lds(
            (const __attribute__((address_space(1))) void*)(gB + (size_t)srow * K + k0 + sc8),
            (__attribute__((address_space(3))) void*)(Bs + t * 8), 16, 0, 0);
        __syncthreads();
        bf16x8 af[2], bfr[2];
#pragma unroll
        for (int mi = 0; mi < 2; ++mi)
            af[mi] = *reinterpret_cast<const bf16x8*>(As + (wm + mi * 16 + l15) * 32 + quad * 8);
#pragma unroll
        for (int ni = 0; ni < 2; ++ni)
            bfr[ni] = *reinterpret_cast<const bf16x8*>(Bs + (wn + ni * 16 + l15) * 32 + quad * 8);
#pragma unroll
        for (int mi = 0; mi < 2; ++mi)
#pragma unroll
            for (int ni = 0; ni < 2; ++ni)
                acc[mi][ni] = __builtin_amdgcn_mfma_f32_16x16x32_bf16(af[mi], bfr[ni], acc[mi][ni], 0, 0, 0);
        __syncthreads();
    }

#pragma unroll
    for (int mi = 0; mi < 2; ++mi) {
        int gr = tileM + wm + mi * 16 + quad * 4;
#pragma unroll
        for (int ni = 0; ni < 2; ++ni) {
            int gc = tileN + wn + ni * 16 + l15;
            if (gc < N) {
                float bb = bias ? bias[gc] : 0.0f;
#pragma unroll
                for (int r = 0; r < 4; ++r) {
                    float v = acc[mi][ni][r] + bb;
                    if (doRelu) v = fmaxf(v, 0.0f);
                    outp[(size_t)(gr + r) * N + gc] = f2b(v);
                }
            }
        }
    }
}

__global__ __launch_bounds__(256) void mega_kernel(
    const float* __restrict__ hidden, const float* __restrict__ emb,
    const float* __restrict__ hW1, const float* __restrict__ hb1,
    const float* __restrict__ hW2, const float* __restrict__ hb2,
    const float* __restrict__ tW1, const float* __restrict__ tb1,
    const float* __restrict__ tW2, const float* __restrict__ tb2,
    const float* __restrict__ bil, const float* __restrict__ lW,
    const float* __restrict__ lb,
    const int* __restrict__ ent_start, const int* __restrict__ ent_label,
    const int* __restrict__ rel_head, const int* __restrict__ rel_tail,
    const int* __restrict__ rel_label,
    float* __restrict__ out, char* __restrict__ ws)
{
    __shared__ SMem sm;
    __shared__ float wsum[4];

    cg::grid_group grid = cg::this_grid();
    const int bx = blockIdx.x, t = threadIdx.x;
    const int G = gridDim.x;
    const int lane = t & 63, wave = t >> 6;

    ushort_t* repE   = (ushort_t*)(ws + 0);         // [2048,1536]
    ushort_t* hW1T   = (ushort_t*)(ws + 6291456);   // [768,1536]
    ushort_t* tW1T   = (ushort_t*)(ws + 8650752);
    ushort_t* hW2T   = (ushort_t*)(ws + 11010048);  // [384,768]
    ushort_t* tW2T   = (ushort_t*)(ws + 11599872);
    ushort_t* BmatT  = (ushort_t*)(ws + 12189696);  // [770,384]
    ushort_t* lWtT   = (ushort_t*)(ws + 12781056);  // [2,384]
    ushort_t* h1     = (ushort_t*)(ws + 12782592);  // [2048,768]
    ushort_t* t1     = (ushort_t*)(ws + 15928320);
    ushort_t* headsE = (ushort_t*)(ws + 19074048);  // [2048,384]
    ushort_t* tailsE = (ushort_t*)(ws + 20646912);
    ushort_t* Uext   = (ushort_t*)(ws + 22219776);  // [2048,770]
    float*    tailLin= (float*)   (ws + 25373696);  // [2048,2]

    // ================= S0: gather + transposes + tails =================
    if (bx == 0 && t == 0) out[0] = 0.0f;
    for (int u = bx; u < 6246; u += G) {
        if (u < 3072) {                               // repE gather, float4
            int idx = u * 256 + t;
            int row = idx / 384, q = idx - row * 384;
            int c = q * 4;
            int b = row >> 7;
            int st = ent_start[row], lab = ent_label[row];
            const float* srcp = (c < 768)
                ? hidden + ((size_t)(b * S_ + st) * D_ + c)
                : emb + ((size_t)lab * D_ + (c - 768));
            float4 v = *reinterpret_cast<const float4*>(srcp);
            uint32_t lo = (uint32_t)f2b(v.x) | ((uint32_t)f2b(v.y) << 16);
            uint32_t hi = (uint32_t)f2b(v.z) | ((uint32_t)f2b(v.w) << 16);
            uint2 pk; pk.x = lo; pk.y = hi;
            *reinterpret_cast<uint2*>(repE + (size_t)idx * 4) = pk;
        } else if (u < 6240) {                        // 32x32 transposes
            int u2 = u - 3072;
            const float* src; ushort_t* dst; int Rr, Cc, base;
            if (u2 < 1152)      { src = hW1;          dst = hW1T;           Rr = 1536; Cc = 768; base = 0; }
            else if (u2 < 2304) { src = tW1;          dst = tW1T;           Rr = 1536; Cc = 768; base = 1152; }
            else if (u2 < 2592) { src = hW2;          dst = hW2T;           Rr = 768;  Cc = 384; base = 2304; }
            else if (u2 < 2880) { src = tW2;          dst = tW2T;           Rr = 768;  Cc = 384; base = 2592; }
            else if (u2 < 3024) { src = bil;          dst = BmatT;          Rr = 384;  Cc = 384; base = 2880; }
            else                { src = bil + 147456; dst = BmatT + 147456; Rr = 384;  Cc = 384; base = 3024; }
            int local = u2 - base, nC = Cc >> 5;
            int tR = (local / nC) * 32, tC = (local - (local / nC) * nC) * 32;
            int tx = t & 31, ty = t >> 5;
#pragma unroll
            for (int r = 0; r < 4; ++r)
                sm.tp[ty + r * 8][tx] = src[(size_t)(tR + ty + r * 8) * Cc + tC + tx];
            __syncthreads();
#pragma unroll
            for (int r = 0; r < 4; ++r)
                dst[(size_t)(tC + ty + r * 8) * Rr + tR + tx] = f2b(sm.tp[tx][ty + r * 8]);
            __syncthreads();
        } else {                                      // tiny tails
            int i2 = (u - 6240) * 256 + t;
            if (i2 < 768) {                           // BmatT rows 768/769
                int o = i2 / 384, kk = i2 - o * 384;
                BmatT[(768 + o) * 384 + kk] = f2b(lW[kk * 2 + o]);
            } else if (i2 < 1536) {                   // lWtT [2,384]
                int j = i2 - 768;
                int o = j / 384, ii = j - o * 384;
                lWtT[o * 384 + ii] = f2b(lW[(384 + ii) * 2 + o]);
            }
        }
    }
    grid.sync();

    // ================= S1: GEMM1  [2048,1536]@[1536,768] x2 towers ======
    for (int u = bx; u < 768; u += G) {
        int z = (u >= 384);
        int r = u - (z ? 384 : 0);
        gemm_unit(repE, z ? tW1T : hW1T, z ? tb1 : hb1, z ? t1 : h1,
                  (r & 31) * 64, (r >> 5) * 64, 768, 1536, 1, sm.g.As, sm.g.Bs, t);
    }
    grid.sync();

    // ================= S2: GEMM2  [2048,768]@[768,384] x2 towers ========
    for (int u = bx; u < 384; u += G) {
        int z = (u >= 192);
        int r = u - (z ? 192 : 0);
        gemm_unit(z ? t1 : h1, z ? tW2T : hW2T, z ? tb2 : hb2, z ? tailsE : headsE,
                  (r & 31) * 64, (r >> 5) * 64, 384, 768, 1, sm.g.As, sm.g.Bs, t);
    }
    grid.sync();

    // ================= S3: GEMM3 (Uext) + tailLin =======================
    for (int u = bx; u < 448; u += G) {
        if (u < 416) {
            gemm_unit(headsE, BmatT, nullptr, Uext,
                      (u & 31) * 64, (u >> 5) * 64, 770, 384, 0, sm.g.As, sm.g.Bs, t);
        } else {
            int w = u - 416;
            int r = w * 64 + (t >> 2), q = t & 3;
            const uint32_t* tv = reinterpret_cast<const uint32_t*>(tailsE + (size_t)r * 384);
            const uint32_t* lw = reinterpret_cast<const uint32_t*>(lWtT);
            float p0 = 0.f, p1 = 0.f;
#pragma unroll 8
            for (int i = q * 48; i < q * 48 + 48; ++i) {
                uint32_t tu = tv[i];
                float tl = bl(tu), th = bh(tu);
                uint32_t l0 = lw[i], l1 = lw[192 + i];
                p0 += tl * bl(l0) + th * bh(l0);
                p1 += tl * bl(l1) + th * bh(l1);
            }
            p0 += __shfl_xor(p0, 1); p0 += __shfl_xor(p0, 2);
            p1 += __shfl_xor(p1, 1); p1 += __shfl_xor(p1, 2);
            if (q == 0) tailLin[2 * r]     = p0;
            if (q == 1) tailLin[2 * r + 1] = p1;
        }
    }
    grid.sync();

    // ================= S4: relations (16-lane groups, 4 rels/wave-iter) =
    float lb0 = lb[0], lb1 = lb[1];
    float lossAcc = 0.0f;
    int l = lane & 15, g = lane >> 4;
    for (int u = bx * 4 + wave; u < 8192; u += G * 4) {
        int rel = u * 4 + g;
        int b = rel >> 11;
        int h = rel_head[rel], tt = rel_tail[rel], lab = rel_label[rel];
        const uint32_t* uh = reinterpret_cast<const uint32_t*>(Uext + (size_t)(b * E_ + h) * 770);
        const uint32_t* tv = reinterpret_cast<const uint32_t*>(tailsE + (size_t)(b * E_ + tt) * 384);
        float a0 = 0.f, a1 = 0.f;
#pragma unroll
        for (int j = 0; j < 12; ++j) {
            int i = l + 16 * j;
            uint32_t tu = tv[i];
            float tl = bl(tu), th = bh(tu);
            uint32_t u0 = uh[i], u1 = uh[192 + i];
            a0 += tl * bl(u0) + th * bh(u0);
            a1 += tl * bl(u1) + th * bh(u1);
        }
#pragma unroll
        for (int d = 1; d < 16; d <<= 1) {
            a0 += __shfl_xor(a0, d);
            a1 += __shfl_xor(a1, d);
        }
        if (l == 0) {
            const ushort_t* uhs = reinterpret_cast<const ushort_t*>(uh);
            int te = b * E_ + tt;
            float l0v = a0 + tailLin[2 * te]     + b2f(uhs[768]) + lb0;
            float l1v = a1 + tailLin[2 * te + 1] + b2f(uhs[769]) + lb1;
            out[1 + 2 * rel]     = l0v;
            out[1 + 2 * rel + 1] = l1v;
            float m = fmaxf(l0v, l1v);
            lossAcc += m + logf(expf(l0v - m) + expf(l1v - m)) - (lab ? l1v : l0v);
        }
    }
    lossAcc += __shfl_xor(lossAcc, 16);
    lossAcc += __shfl_xor(lossAcc, 32);
    if (lane == 0) wsum[wave] = lossAcc;
    __syncthreads();
    if (t == 0)
        atomicAdd(out, (wsum[0] + wsum[1] + wsum[2] + wsum[3]) * (1.0f / 32768.0f));
}

// ---------------------------------------------------------------------------
extern "C" void kernel_launch(void* const* d_in, const int* in_sizes, int n_in,
                              void* d_out, int out_size, void* d_ws, size_t ws_size,
                              hipStream_t stream)
{
    const float* hidden = (const float*)d_in[0];
    const float* emb    = (const float*)d_in[1];
    const float* hW1    = (const float*)d_in[2];
    const float* hb1    = (const float*)d_in[3];
    const float* hW2    = (const float*)d_in[4];
    const float* hb2    = (const float*)d_in[5];
    const float* tW1    = (const float*)d_in[6];
    const float* tb1    = (const float*)d_in[7];
    const float* tW2    = (const float*)d_in[8];
    const float* tb2    = (const float*)d_in[9];
    const float* bil    = (const float*)d_in[10];
    const float* lW     = (const float*)d_in[11];
    const float* lb     = (const float*)d_in[12];
    const int* ent_start = (const int*)d_in[13];
    const int* ent_label = (const int*)d_in[14];
    const int* rel_head  = (const int*)d_in[15];
    const int* rel_tail  = (const int*)d_in[16];
    const int* rel_label = (const int*)d_in[17];
    float* out = (float*)d_out;
    char* ws = (char*)d_ws;

    // Capture-safe host-side occupancy query: grid = min(maxB,4) * 256 CUs
    // guarantees all blocks co-resident so cooperative launch can't be
    // rejected for size (round-4 failure mode).
    int maxB = 0;
    if (hipOccupancyMaxActiveBlocksPerMultiprocessor(&maxB, mega_kernel, 256, 0)
            != hipSuccess || maxB < 1)
        maxB = 1;
    int perCU = maxB < 4 ? maxB : 4;
    dim3 grid(perCU * 256);

    void* args[] = {
        (void*)&hidden, (void*)&emb, (void*)&hW1, (void*)&hb1, (void*)&hW2, (void*)&hb2,
        (void*)&tW1, (void*)&tb1, (void*)&tW2, (void*)&tb2, (void*)&bil, (void*)&lW,
        (void*)&lb, (void*)&ent_start, (void*)&ent_label, (void*)&rel_head,
        (void*)&rel_tail, (void*)&rel_label, (void*)&out, (void*)&ws
    };
    hipLaunchCooperativeKernel((void*)mega_kernel, grid, dim3(256),
                               args, 0, stream);
}

// Round 6
// 181.617 us; speedup vs baseline: 2.0515x; 2.0515x over previous
//
#include <hip/hip_runtime.h>
#include <hip/hip_bf16.h>
#include <cstdint>

typedef unsigned short ushort_t;
typedef __bf16 bf16x8 __attribute__((ext_vector_type(8)));
typedef float f32x4 __attribute__((ext_vector_type(4)));

#define B_   16
#define S_   512
#define D_   768
#define E_   128

__device__ inline ushort_t f2b(float f) {
    uint32_t u = __builtin_bit_cast(uint32_t, f);
    uint32_t r = (u + 0x7fffu + ((u >> 16) & 1u)) >> 16;   // RNE
    return (ushort_t)r;
}
__device__ inline float b2f(ushort_t u) {
    uint32_t v = ((uint32_t)u) << 16;
    return __builtin_bit_cast(float, v);
}
__device__ inline float bl(uint32_t u) {
    uint32_t v = u << 16;
    return __builtin_bit_cast(float, v);
}
__device__ inline float bh(uint32_t u) {
    uint32_t v = u & 0xffff0000u;
    return __builtin_bit_cast(float, v);
}

// ---------------------------------------------------------------------------
// Prep (merged): one 256-thread work unit per block.
//   units [0,3072):    repE gather (float4 -> bf16)
//   units [3072,6240): 32x32 LDS-tile weight transposes fp32 -> bf16
//   units [6240,6246): tiny tails (BmatT rows 768/769, lWtT)
// ---------------------------------------------------------------------------
__global__ __launch_bounds__(256) void prep_all(
    const float* __restrict__ hidden, const float* __restrict__ emb,
    const float* __restrict__ hW1, const float* __restrict__ tW1,
    const float* __restrict__ hW2, const float* __restrict__ tW2,
    const float* __restrict__ bil, const float* __restrict__ lW,
    const int* __restrict__ ent_start, const int* __restrict__ ent_label,
    ushort_t* __restrict__ repE, ushort_t* __restrict__ hW1T, ushort_t* __restrict__ tW1T,
    ushort_t* __restrict__ hW2T, ushort_t* __restrict__ tW2T,
    ushort_t* __restrict__ BmatT, ushort_t* __restrict__ lWtT, float* __restrict__ out)
{
    __shared__ float tp[32][33];
    const int u = blockIdx.x, t = threadIdx.x;
    if (u == 0 && t == 0) out[0] = 0.0f;

    if (u < 3072) {                               // repE gather
        int idx = u * 256 + t;
        int row = idx / 384, q = idx - row * 384;
        int c = q * 4;
        int b = row >> 7;
        int st = ent_start[row], lab = ent_label[row];
        const float* srcp = (c < 768)
            ? hidden + ((size_t)(b * S_ + st) * D_ + c)
            : emb + ((size_t)lab * D_ + (c - 768));
        float4 v = *reinterpret_cast<const float4*>(srcp);
        uint32_t lo = (uint32_t)f2b(v.x) | ((uint32_t)f2b(v.y) << 16);
        uint32_t hi = (uint32_t)f2b(v.z) | ((uint32_t)f2b(v.w) << 16);
        uint2 pk; pk.x = lo; pk.y = hi;
        *reinterpret_cast<uint2*>(repE + (size_t)idx * 4) = pk;
        return;
    }
    if (u < 6240) {                               // transposes
        int u2 = u - 3072;
        const float* src; ushort_t* dst; int Rr, Cc, base;
        if (u2 < 1152)      { src = hW1;          dst = hW1T;           Rr = 1536; Cc = 768; base = 0; }
        else if (u2 < 2304) { src = tW1;          dst = tW1T;           Rr = 1536; Cc = 768; base = 1152; }
        else if (u2 < 2592) { src = hW2;          dst = hW2T;           Rr = 768;  Cc = 384; base = 2304; }
        else if (u2 < 2880) { src = tW2;          dst = tW2T;           Rr = 768;  Cc = 384; base = 2592; }
        else if (u2 < 3024) { src = bil;          dst = BmatT;          Rr = 384;  Cc = 384; base = 2880; }
        else                { src = bil + 147456; dst = BmatT + 147456; Rr = 384;  Cc = 384; base = 3024; }
        int local = u2 - base, nC = Cc >> 5;
        int tR = (local / nC) * 32, tC = (local - (local / nC) * nC) * 32;
        int tx = t & 31, ty = t >> 5;
#pragma unroll
        for (int r = 0; r < 4; ++r)
            tp[ty + r * 8][tx] = src[(size_t)(tR + ty + r * 8) * Cc + tC + tx];
        __syncthreads();
#pragma unroll
        for (int r = 0; r < 4; ++r)
            dst[(size_t)(tC + ty + r * 8) * Rr + tR + tx] = f2b(tp[tx][ty + r * 8]);
        return;
    }
    int i2 = (u - 6240) * 256 + t;                // tails
    if (i2 < 768) {                               // BmatT rows 768/769
        int o = i2 / 384, kk = i2 - o * 384;
        BmatT[(768 + o) * 384 + kk] = f2b(lW[kk * 2 + o]);
    } else if (i2 < 1536) {                       // lWtT [2,384]
        int j = i2 - 768;
        int o = j / 384, ii = j - o * 384;
        lWtT[o * 384 + ii] = f2b(lW[(384 + ii) * 2 + o]);
    }
}

// ---------------------------------------------------------------------------
// LDS-staged bf16 MFMA GEMM, 64x64 block tile (wave tile 32x32, BK=32).
// A [M,K] row-major, Bt [N,K] row-major. blockIdx.z selects operand set.
// ---------------------------------------------------------------------------
__global__ __launch_bounds__(256) void gemm_lds(
    const ushort_t* __restrict__ A0, const ushort_t* __restrict__ A1,
    const ushort_t* __restrict__ Bt0, const ushort_t* __restrict__ Bt1,
    const float* __restrict__ bias0, const float* __restrict__ bias1,
    ushort_t* __restrict__ out0, ushort_t* __restrict__ out1,
    int M, int N, int K, int doRelu)
{
    __shared__ ushort_t As[64 * 32];
    __shared__ ushort_t Bs[64 * 32];
    const ushort_t* A   = blockIdx.z ? A1 : A0;
    const ushort_t* Bt  = blockIdx.z ? Bt1 : Bt0;
    const float*   bias = blockIdx.z ? bias1 : bias0;
    ushort_t*      out  = blockIdx.z ? out1 : out0;

    int t = threadIdx.x;
    int lane = t & 63, wave = t >> 6;
    int tileM = blockIdx.x * 64, tileN = blockIdx.y * 64;
    int wm = (wave >> 1) * 32, wn = (wave & 1) * 32;
    int l15 = lane & 15, quad = lane >> 4;
    int srow = t >> 2, sc8 = (t & 3) << 3;

    const ushort_t* gA = A  + (size_t)tileM * K;
    const ushort_t* gB = Bt + (size_t)tileN * K;

    f32x4 acc[2][2];
#pragma unroll
    for (int a = 0; a < 2; ++a)
#pragma unroll
        for (int b = 0; b < 2; ++b) {
            acc[a][b][0] = 0.f; acc[a][b][1] = 0.f;
            acc[a][b][2] = 0.f; acc[a][b][3] = 0.f;
        }

    for (int k0 = 0; k0 < K; k0 += 32) {
        __builtin_amdgcn_global_load_lds(
            (const __attribute__((address_space(1))) void*)(gA + (size_t)srow * K + k0 + sc8),
            (__attribute__((address_space(3))) void*)(As + t * 8), 16, 0, 0);
        __builtin_amdgcn_global_load_lds(
            (const __attribute__((address_space(1))) void*)(gB + (size_t)srow * K + k0 + sc8),
            (__attribute__((address_space(3))) void*)(Bs + t * 8), 16, 0, 0);
        __syncthreads();
        bf16x8 af[2], bfr[2];
#pragma unroll
        for (int mi = 0; mi < 2; ++mi)
            af[mi] = *reinterpret_cast<const bf16x8*>(As + (wm + mi * 16 + l15) * 32 + quad * 8);
#pragma unroll
        for (int ni = 0; ni < 2; ++ni)
            bfr[ni] = *reinterpret_cast<const bf16x8*>(Bs + (wn + ni * 16 + l15) * 32 + quad * 8);
#pragma unroll
        for (int mi = 0; mi < 2; ++mi)
#pragma unroll
            for (int ni = 0; ni < 2; ++ni)
                acc[mi][ni] = __builtin_amdgcn_mfma_f32_16x16x32_bf16(af[mi], bfr[ni], acc[mi][ni], 0, 0, 0);
        __syncthreads();
    }

#pragma unroll
    for (int mi = 0; mi < 2; ++mi) {
        int gr = tileM + wm + mi * 16 + quad * 4;
#pragma unroll
        for (int ni = 0; ni < 2; ++ni) {
            int gc = tileN + wn + ni * 16 + l15;
            if (gc < N) {
                float bb = bias ? bias[gc] : 0.0f;
#pragma unroll
                for (int r = 0; r < 4; ++r) {
                    float v = acc[mi][ni][r] + bb;
                    if (doRelu) v = fmaxf(v, 0.0f);
                    out[(size_t)(gr + r) * N + gc] = f2b(v);
                }
            }
        }
    }
}

// ---------------------------------------------------------------------------
// GEMM3 (Uext = headsE @ BmatT^T, no bias) + fused tailLin precompute.
// grid (32, 14): by<13 -> gemm tile; by==13 -> tailLin for 64 entities.
// ---------------------------------------------------------------------------
__global__ __launch_bounds__(256) void gemm3_tail(
    const ushort_t* __restrict__ headsE, const ushort_t* __restrict__ BmatT,
    const ushort_t* __restrict__ tailsE, const ushort_t* __restrict__ lWtT,
    ushort_t* __restrict__ Uext, float* __restrict__ tailLin)
{
    const int t = threadIdx.x;
    if (blockIdx.y == 13) {                       // tailLin: 32 blocks x 64 rows
        int r = blockIdx.x * 64 + (t >> 2), q = t & 3;
        const uint32_t* tv = reinterpret_cast<const uint32_t*>(tailsE + (size_t)r * 384);
        const uint32_t* lw = reinterpret_cast<const uint32_t*>(lWtT);
        float p0 = 0.f, p1 = 0.f;
#pragma unroll 8
        for (int i = q * 48; i < q * 48 + 48; ++i) {
            uint32_t tu = tv[i];
            float tl = bl(tu), th = bh(tu);
            uint32_t l0 = lw[i], l1 = lw[192 + i];
            p0 += tl * bl(l0) + th * bh(l0);
            p1 += tl * bl(l1) + th * bh(l1);
        }
        p0 += __shfl_xor(p0, 1); p0 += __shfl_xor(p0, 2);
        p1 += __shfl_xor(p1, 1); p1 += __shfl_xor(p1, 2);
        if (q == 0) tailLin[2 * r]     = p0;
        if (q == 1) tailLin[2 * r + 1] = p1;
        return;
    }

    __shared__ ushort_t As[64 * 32];
    __shared__ ushort_t Bs[64 * 32];
    const int K = 384, N = 770;
    int lane = t & 63, wave = t >> 6;
    int tileM = blockIdx.x * 64, tileN = blockIdx.y * 64;
    int wm = (wave >> 1) * 32, wn = (wave & 1) * 32;
    int l15 = lane & 15, quad = lane >> 4;
    int srow = t >> 2, sc8 = (t & 3) << 3;

    const ushort_t* gA = headsE + (size_t)tileM * K;
    const ushort_t* gB = BmatT  + (size_t)tileN * K;

    f32x4 acc[2][2];
#pragma unroll
    for (int a = 0; a < 2; ++a)
#pragma unroll
        for (int b = 0; b < 2; ++b) {
            acc[a][b][0] = 0.f; acc[a][b][1] = 0.f;
            acc[a][b][2] = 0.f; acc[a][b][3] = 0.f;
        }

    for (int k0 = 0; k0 < K; k0 += 32) {
        __builtin_amdgcn_global_load_lds(
            (const __attribute__((address_space(1))) void*)(gA + (size_t)srow * K + k0 + sc8),
            (__attribute__((address_space(3))) void*)(As + t * 8), 16, 0, 0);
        __builtin_amdgcn_global_load_lds(
            (const __attribute__((address_space(1))) void*)(gB + (size_t)srow * K + k0 + sc8),
            (__attribute__((address_space(3))) void*)(Bs + t * 8), 16, 0, 0);
        __syncthreads();
        bf16x8 af[2], bfr[2];
#pragma unroll
        for (int mi = 0; mi < 2; ++mi)
            af[mi] = *reinterpret_cast<const bf16x8*>(As + (wm + mi * 16 + l15) * 32 + quad * 8);
#pragma unroll
        for (int ni = 0; ni < 2; ++ni)
            bfr[ni] = *reinterpret_cast<const bf16x8*>(Bs + (wn + ni * 16 + l15) * 32 + quad * 8);
#pragma unroll
        for (int mi = 0; mi < 2; ++mi)
#pragma unroll
            for (int ni = 0; ni < 2; ++ni)
                acc[mi][ni] = __builtin_amdgcn_mfma_f32_16x16x32_bf16(af[mi], bfr[ni], acc[mi][ni], 0, 0, 0);
        __syncthreads();
    }

#pragma unroll
    for (int mi = 0; mi < 2; ++mi) {
        int gr = tileM + wm + mi * 16 + quad * 4;
#pragma unroll
        for (int ni = 0; ni < 2; ++ni) {
            int gc = tileN + wn + ni * 16 + l15;
            if (gc < N) {
#pragma unroll
                for (int r = 0; r < 4; ++r)
                    Uext[(size_t)(gr + r) * N + gc] = f2b(acc[mi][ni][r]);
            }
        }
    }
}

// ---------------------------------------------------------------------------
// Relations: 16-lane groups, 4 relations per wave in flight. Grid 2048.
// ---------------------------------------------------------------------------
__global__ __launch_bounds__(256) void rel16_kernel(
    const ushort_t* __restrict__ Uext, const ushort_t* __restrict__ tailsE,
    const float* __restrict__ tailLin, const float* __restrict__ lb,
    const int* __restrict__ rel_head, const int* __restrict__ rel_tail,
    const int* __restrict__ rel_label, float* __restrict__ out)
{
    __shared__ float wsum[4];
    const int t = threadIdx.x;
    int lane = t & 63, wave = t >> 6;
    int l = lane & 15, g = lane >> 4;
    float lb0 = lb[0], lb1 = lb[1];
    float lossAcc = 0.0f;

    int rel = (blockIdx.x * 4 + wave) * 4 + g;
    int b = rel >> 11;
    int h = rel_head[rel], tt = rel_tail[rel], lab = rel_label[rel];
    const uint32_t* uh = reinterpret_cast<const uint32_t*>(Uext + (size_t)(b * E_ + h) * 770);
    const uint32_t* tv = reinterpret_cast<const uint32_t*>(tailsE + (size_t)(b * E_ + tt) * 384);
    float a0 = 0.f, a1 = 0.f;
#pragma unroll
    for (int j = 0; j < 12; ++j) {
        int i = l + 16 * j;
        uint32_t tu = tv[i];
        float tl = bl(tu), th = bh(tu);
        uint32_t u0 = uh[i], u1 = uh[192 + i];
        a0 += tl * bl(u0) + th * bh(u0);
        a1 += tl * bl(u1) + th * bh(u1);
    }
#pragma unroll
    for (int d = 1; d < 16; d <<= 1) {
        a0 += __shfl_xor(a0, d);
        a1 += __shfl_xor(a1, d);
    }
    if (l == 0) {
        const ushort_t* uhs = reinterpret_cast<const ushort_t*>(uh);
        int te = b * E_ + tt;
        float l0v = a0 + tailLin[2 * te]     + b2f(uhs[768]) + lb0;
        float l1v = a1 + tailLin[2 * te + 1] + b2f(uhs[769]) + lb1;
        out[1 + 2 * rel]     = l0v;
        out[1 + 2 * rel + 1] = l1v;
        float m = fmaxf(l0v, l1v);
        lossAcc = m + logf(expf(l0v - m) + expf(l1v - m)) - (lab ? l1v : l0v);
    }
    lossAcc += __shfl_xor(lossAcc, 16);
    lossAcc += __shfl_xor(lossAcc, 32);
    if (lane == 0) wsum[wave] = lossAcc;
    __syncthreads();
    if (t == 0)
        atomicAdd(out, (wsum[0] + wsum[1] + wsum[2] + wsum[3]) * (1.0f / 32768.0f));
}

// ---------------------------------------------------------------------------
extern "C" void kernel_launch(void* const* d_in, const int* in_sizes, int n_in,
                              void* d_out, int out_size, void* d_ws, size_t ws_size,
                              hipStream_t stream)
{
    const float* hidden = (const float*)d_in[0];
    const float* emb    = (const float*)d_in[1];
    const float* hW1    = (const float*)d_in[2];
    const float* hb1    = (const float*)d_in[3];
    const float* hW2    = (const float*)d_in[4];
    const float* hb2    = (const float*)d_in[5];
    const float* tW1    = (const float*)d_in[6];
    const float* tb1    = (const float*)d_in[7];
    const float* tW2    = (const float*)d_in[8];
    const float* tb2    = (const float*)d_in[9];
    const float* bil    = (const float*)d_in[10];
    const float* lW     = (const float*)d_in[11];
    const float* lb     = (const float*)d_in[12];
    const int* ent_start = (const int*)d_in[13];
    const int* ent_label = (const int*)d_in[14];
    const int* rel_head  = (const int*)d_in[15];
    const int* rel_tail  = (const int*)d_in[16];
    const int* rel_label = (const int*)d_in[17];
    float* out = (float*)d_out;

    char* ws = (char*)d_ws;
    ushort_t* repE   = (ushort_t*)(ws + 0);         // [2048,1536]
    ushort_t* hW1T   = (ushort_t*)(ws + 6291456);   // [768,1536]
    ushort_t* tW1T   = (ushort_t*)(ws + 8650752);
    ushort_t* hW2T   = (ushort_t*)(ws + 11010048);  // [384,768]
    ushort_t* tW2T   = (ushort_t*)(ws + 11599872);
    ushort_t* BmatT  = (ushort_t*)(ws + 12189696);  // [770,384]
    ushort_t* lWtT   = (ushort_t*)(ws + 12781056);  // [2,384]
    ushort_t* h1     = (ushort_t*)(ws + 12782592);  // [2048,768]
    ushort_t* t1     = (ushort_t*)(ws + 15928320);
    ushort_t* headsE = (ushort_t*)(ws + 19074048);  // [2048,384]
    ushort_t* tailsE = (ushort_t*)(ws + 20646912);
    ushort_t* Uext   = (ushort_t*)(ws + 22219776);  // [2048,770]
    float*    tailLin= (float*)   (ws + 25373696);  // [2048,2]

    prep_all<<<6246, 256, 0, stream>>>(
        hidden, emb, hW1, tW1, hW2, tW2, bil, lW, ent_start, ent_label,
        repE, hW1T, tW1T, hW2T, tW2T, BmatT, lWtT, out);

    gemm_lds<<<dim3(32, 12, 2), 256, 0, stream>>>(
        repE, repE, hW1T, tW1T, hb1, tb1, h1, t1, 2048, 768, 1536, 1);

    gemm_lds<<<dim3(32, 6, 2), 256, 0, stream>>>(
        h1, t1, hW2T, tW2T, hb2, tb2, headsE, tailsE, 2048, 384, 768, 1);

    gemm3_tail<<<dim3(32, 14, 1), 256, 0, stream>>>(
        headsE, BmatT, tailsE, lWtT, Uext, tailLin);

    rel16_kernel<<<2048, 256, 0, stream>>>(
        Uext, tailsE, tailLin, lb, rel_head, rel_tail, rel_label, out);
}